// Round 1
// baseline (4717.137 us; speedup 1.0000x reference)
//
#include <hip/hip_runtime.h>
#include <hip/hip_bf16.h>
#include <cstdint>

#define C_NU 100000
#define C_NI 100000
#define C_DIM 64
#define C_Q 5
#define C_NE 2000000
#define C_B 4096
#define C_P 10

// ---------------- Threefry-2x32 (JAX-compatible), 20 rounds ----------------
__host__ __device__ static inline void tf2x32(uint32_t k0, uint32_t k1,
                                              uint32_t& x0, uint32_t& x1) {
  uint32_t k2 = k0 ^ k1 ^ 0x1BD11BDAu;
#define TFR(r) { x0 += x1; x1 = (x1 << r) | (x1 >> (32 - r)); x1 ^= x0; }
  x0 += k0; x1 += k1;
  TFR(13) TFR(15) TFR(26) TFR(6)
  x0 += k1; x1 += k2 + 1u;
  TFR(17) TFR(29) TFR(16) TFR(24)
  x0 += k2; x1 += k0 + 2u;
  TFR(13) TFR(15) TFR(26) TFR(6)
  x0 += k0; x1 += k1 + 3u;
  TFR(17) TFR(29) TFR(16) TFR(24)
  x0 += k1; x1 += k2 + 4u;
  TFR(13) TFR(15) TFR(26) TFR(6)
  x0 += k2; x1 += k0 + 5u;
#undef TFR
}

// partitionable-mode random bits at flat index idx (hi counter = 0)
__device__ static inline float tf_uniform(uint32_t k0, uint32_t k1, uint32_t idx) {
  uint32_t x0 = 0u, x1 = idx;
  tf2x32(k0, k1, x0, x1);
  uint32_t bits = x0 ^ x1;
  return __uint_as_float((bits >> 9) | 0x3F800000u) - 1.0f;
}

__device__ static inline float leaky(float x) { return x >= 0.f ? x : 0.5f * x; }

// ---------------- constant maps for the 16 info_nce calls ----------------
// normbuf slots: 0:Zu1 1:Zu2 2:Zi1 3:Zi2 4:Zdu1 5:Zdu2 6:Zdi1 7:Zdi2 8:Gu1 9:Gu2 10:Gi1 11:Gi2
__constant__ int c_gsel[16] = {0,1,2,3, 0,2, 4,5,6,7, 4,6, 0,1,2,3};
__constant__ int c_hsrc[16] = {8,9,10,11, 1,3, 8,9,10,11, 5,7, 4,5,6,7};
// W order: 0:ng0 1:ng1 2:nn 3:dg0 4:dg1 5:dd 6:nd0 7:nd1
__constant__ int c_wsel[16] = {0,1,0,1, 2,2, 3,4,3,4, 5,5, 6,7,6,7};
// slots: 0:n 1:d 2:nn 3:dd 4:nd (5: loss_r sum)
__constant__ int c_slot[16] = {0,0,0,0, 2,2, 1,1,1,1, 3,3, 4,4,4,4};

struct WPtrs { const float* W[8]; };
struct NceKeys { uint32_t k0[16]; uint32_t k1[16]; };

// ---------------- kernels ----------------

// fused spmm: Zacc[dst] += vals[e]*Ein[src]; Zdacc[dst] += dropout(vals[e])*Ein[src]
__global__ __launch_bounds__(256) void spmm_kernel(
    const float* __restrict__ vals, const int* __restrict__ gidx,
    const int* __restrict__ sidx, const float* __restrict__ Ein,
    float* __restrict__ Zacc, float* __restrict__ Zdacc,
    uint32_t dk0, uint32_t dk1) {
  long long t = (long long)blockIdx.x * blockDim.x + threadIdx.x;
  int e = (int)(t >> 6);
  int d = (int)(t & 63);
  if (e >= C_NE) return;
  int src = gidx[e];
  int dst = sidx[e];
  float v = vals[e];
  float u = tf_uniform(dk0, dk1, (uint32_t)e);
  float vd = (u < 0.9f) ? (v / 0.9f) : 0.0f;
  float x = Ein[(size_t)src * 64 + d];
  atomicAdd(&Zacc[(size_t)dst * 64 + d], v * x);
  atomicAdd(&Zdacc[(size_t)dst * 64 + d], vd * x);
}

// M[q][d] = sum_n T[q][n] * E[n][d]   (T is [5][n] row-major)
__global__ __launch_bounds__(256) void svd_reduce(
    const float* __restrict__ T, const float* __restrict__ E,
    float* __restrict__ M, int n) {
  int wid = (int)(((long long)blockIdx.x * blockDim.x + threadIdx.x) >> 6);
  int lane = threadIdx.x & 63;
  int nw = (gridDim.x * blockDim.x) >> 6;
  float acc[5] = {0.f, 0.f, 0.f, 0.f, 0.f};
  for (int i = wid; i < n; i += nw) {
    float x = E[(size_t)i * 64 + lane];
#pragma unroll
    for (int q = 0; q < 5; ++q) acc[q] += T[(size_t)q * n + i] * x;
  }
#pragma unroll
  for (int q = 0; q < 5; ++q) atomicAdd(&M[q * 64 + lane], acc[q]);
}

// act + noise on Zacc, act on Zdacc, E update (in place) and E running sum
__global__ __launch_bounds__(256) void act_noise_update(
    float* __restrict__ Zacc, float* __restrict__ Zdacc,
    float* __restrict__ Ecur, float* __restrict__ Esum,
    uint32_t nk0, uint32_t nk1, int n) {
  long long t = (long long)blockIdx.x * blockDim.x + threadIdx.x;
  int r = (int)(t >> 6);
  int d = (int)(t & 63);
  if (r >= n) return;
  size_t j = (size_t)r * 64 + d;
  float u = tf_uniform(nk0, nk1, (uint32_t)j);
  float ss = u * u;
#pragma unroll
  for (int off = 1; off < 64; off <<= 1) ss += __shfl_xor(ss, off);
  float nrm = fmaxf(sqrtf(ss), 1e-12f);
  float z = leaky(Zacc[j]);
  float sg = (z > 0.f) ? 1.f : (z < 0.f ? -1.f : 0.f);
  z += sg * (u / nrm) * 0.1f;
  float zd = leaky(Zdacc[j]);
  Zacc[j] = z;
  Zdacc[j] = zd;
  float en = z + zd + Ecur[j];
  Ecur[j] = en;
  Esum[j] += en;
}

// gather batch rows & L2-normalize; blockIdx.y selects {Z, Zd, G}
__global__ __launch_bounds__(256) void gather_norm(
    const int* __restrict__ ids, const float* __restrict__ Z,
    const float* __restrict__ Zd, const float* __restrict__ mul_s,
    const float* __restrict__ M, float* __restrict__ oZ,
    float* __restrict__ oZd, float* __restrict__ oG) {
  long long t = (long long)blockIdx.x * blockDim.x + threadIdx.x;
  int b = (int)(t >> 6);
  int d = (int)(t & 63);
  if (b >= C_B) return;
  int id = ids[b];
  float v;
  float* out;
  if (blockIdx.y == 0) { v = Z[(size_t)id * 64 + d]; out = oZ; }
  else if (blockIdx.y == 1) { v = Zd[(size_t)id * 64 + d]; out = oZd; }
  else {
    float s = 0.f;
#pragma unroll
    for (int q = 0; q < 5; ++q) s += mul_s[(size_t)id * 5 + q] * M[q * 64 + d];
    v = leaky(s);
    out = oG;
  }
  float ss = v * v;
#pragma unroll
  for (int off = 1; off < 64; off <<= 1) ss += __shfl_xor(ss, off);
  float nrm = fmaxf(sqrtf(ss), 1e-12f);
  out[(size_t)b * 64 + d] = v / nrm;
}

// hyper[call] = normbuf[hsrc[call]] @ W[wsel[call]]
__global__ __launch_bounds__(256) void hyper_kernel(
    const float* __restrict__ normbuf, float* __restrict__ hyper, WPtrs wp) {
  int call = blockIdx.y;
  long long t = (long long)blockIdx.x * blockDim.x + threadIdx.x;
  int b = (int)(t >> 6);
  int d = (int)(t & 63);
  if (b >= C_B) return;
  const float* xn = normbuf + (size_t)c_hsrc[call] * C_B * 64 + (size_t)b * 64;
  const float* W = wp.W[c_wsel[call]];
  float x = xn[d];
  float h = 0.f;
  for (int k = 0; k < 64; ++k) {
    float xk = __shfl(x, k);
    h += xk * W[k * 64 + d];
  }
  hyper[(size_t)call * C_B * 64 + (size_t)b * 64 + d] = h;
}

// LDS chunk swizzle: spreads strided row reads across banks
__device__ static inline int swz(int r, int c) {
  int chunk = (c >> 2) ^ ((r + (r >> 2)) & 15);
  return r * 64 + (chunk << 2) + (c & 3);
}
__device__ static inline int swz4(int r, int k4) {
  return r * 64 + (((k4 ^ ((r + (r >> 2)) & 15))) << 2);
}

// fused info_nce: scores=gnn@hyper^T, exp, row-sum, diag, mask, reduce
__global__ __launch_bounds__(256) void nce_kernel(
    const float* __restrict__ normbuf, const float* __restrict__ hyper,
    float* __restrict__ slots, NceKeys nk) {
  const int call = blockIdx.y;
  const float* G = normbuf + (size_t)c_gsel[call] * C_B * 64;
  const float* H = hyper + (size_t)call * C_B * 64;
  const int br = blockIdx.x * 64;
  __shared__ float Gt[64 * 64];
  __shared__ float Ht[64 * 64];
  __shared__ float red[64][17];
  __shared__ float posr[64];
  const int tid = threadIdx.x;
  for (int i = tid; i < 64 * 64; i += 256) {
    int r = i >> 6, c = i & 63;
    Gt[swz(r, c)] = G[(size_t)(br + r) * 64 + c];
  }
  const int ty = tid >> 4, tx = tid & 15;
  float rs[4] = {0.f, 0.f, 0.f, 0.f};
  float ps[4] = {0.f, 0.f, 0.f, 0.f};
  for (int jt = 0; jt < C_B / 64; ++jt) {
    __syncthreads();
    for (int i = tid; i < 64 * 64; i += 256) {
      int r = i >> 6, c = i & 63;
      Ht[swz(r, c)] = H[(size_t)(jt * 64 + r) * 64 + c];
    }
    __syncthreads();
    float s[4][4] = {};
    for (int k4 = 0; k4 < 16; ++k4) {
      float4 g[4], h[4];
#pragma unroll
      for (int i = 0; i < 4; ++i) g[i] = *(const float4*)&Gt[swz4(ty * 4 + i, k4)];
#pragma unroll
      for (int j = 0; j < 4; ++j) h[j] = *(const float4*)&Ht[swz4(tx * 4 + j, k4)];
#pragma unroll
      for (int i = 0; i < 4; ++i)
#pragma unroll
        for (int j = 0; j < 4; ++j)
          s[i][j] += g[i].x * h[j].x + g[i].y * h[j].y + g[i].z * h[j].z + g[i].w * h[j].w;
    }
#pragma unroll
    for (int i = 0; i < 4; ++i) {
      int grow = br + ty * 4 + i;
#pragma unroll
      for (int j = 0; j < 4; ++j) {
        float e = __expf(s[i][j] * 5.0f);  // /TEMP
        rs[i] += e;
        if (jt * 64 + tx * 4 + j == grow) ps[i] = e;
      }
    }
  }
#pragma unroll
  for (int i = 0; i < 4; ++i) {
    red[ty * 4 + i][tx] = rs[i];
    if (ps[i] != 0.f) posr[ty * 4 + i] = ps[i];
  }
  __syncthreads();
  if (tid < 64) {
    float ns = 0.f;
#pragma unroll
    for (int k = 0; k < 16; ++k) ns += red[tid][k];
    float p = posr[tid];
    float v = -__logf(p / (ns + 1e-8f) + 1e-8f);
    int b = br + tid;
    float u = tf_uniform(nk.k0[call], nk.k1[call], (uint32_t)b);
    float contrib = (u > 0.5f) ? v : 0.f;
    for (int off = 32; off; off >>= 1) contrib += __shfl_down(contrib, off);
    if (tid == 0) atomicAdd(&slots[c_slot[call]], contrib);
  }
}

__global__ __launch_bounds__(256) void loss_r_kernel(
    const float* __restrict__ Eu, const float* __restrict__ Ei,
    const int* __restrict__ uids, const int* __restrict__ pos,
    const int* __restrict__ neg, float* __restrict__ slots) {
  long long t = (long long)blockIdx.x * blockDim.x + threadIdx.x;
  int b = (int)(t >> 6);
  int d = (int)(t & 63);
  if (b >= C_B) return;
  float u = Eu[(size_t)uids[b] * 64 + d];
  float bpr = 0.f, pmin = 3.4e38f, nmax = -3.4e38f;
  for (int p = 0; p < C_P; ++p) {
    float pe = Ei[(size_t)pos[b * C_P + p] * 64 + d];
    float ne = Ei[(size_t)neg[b * C_P + p] * 64 + d];
    float psc = u * pe, nsc = u * ne;
#pragma unroll
    for (int off = 1; off < 64; off <<= 1) {
      psc += __shfl_xor(psc, off);
      nsc += __shfl_xor(nsc, off);
    }
    pmin = fminf(pmin, psc);
    nmax = fmaxf(nmax, nsc);
    bpr += fmaxf(1.f - psc + nsc, 0.f);
  }
  if (d == 0) {
    float hd = (nmax - pmin > 0.005f) ? 10.f * (nmax - pmin) : 0.f;
    atomicAdd(&slots[5], bpr + hd);
  }
}

__global__ void final_kernel(const float* __restrict__ slots, float* __restrict__ out) {
  if (threadIdx.x == 0 && blockIdx.x == 0) {
    float n = slots[0], dl = slots[1], nn = slots[2], dd = slots[3], nd = slots[4];
    float lr = slots[5] / (float)C_B;
    out[0] = lr + 0.2f * (n + dl) + 0.2f * (nn + dd + nd);
    out[1] = lr;
    out[2] = dl;
    out[3] = n;
  }
}

// ---------------- host ----------------
extern "C" void kernel_launch(void* const* d_in, const int* in_sizes, int n_in,
                              void* d_out, int out_size, void* d_ws, size_t ws_size,
                              hipStream_t stream) {
  (void)in_sizes; (void)n_in; (void)out_size;
  const float* E_u_0   = (const float*)d_in[0];
  const float* E_i_0   = (const float*)d_in[1];
  const float* adjvals = (const float*)d_in[2];
  const float* u_mul_s = (const float*)d_in[3];
  const float* v_mul_s = (const float*)d_in[4];
  const float* ut      = (const float*)d_in[5];
  const float* vt      = (const float*)d_in[6];
  const float* W_nn    = (const float*)d_in[7];
  const float* W_dd    = (const float*)d_in[8];
  const float* W_ng    = (const float*)d_in[9];
  const float* W_dg    = (const float*)d_in[10];
  const float* W_nd    = (const float*)d_in[11];
  const int* adj_rows  = (const int*)d_in[12];
  const int* adj_cols  = (const int*)d_in[13];
  const int* uids      = (const int*)d_in[14];
  const int* iids      = (const int*)d_in[15];
  const int* pos       = (const int*)d_in[16];
  const int* neg       = (const int*)d_in[17];
  float* out = (float*)d_out;

  const size_t NU64 = (size_t)C_NU * 64;
  const size_t NI64 = (size_t)C_NI * 64;
  const size_t B64  = (size_t)C_B * 64;

  float* w = (float*)d_ws;
  float* Eu_cur = w; w += NU64;
  float* Ei_cur = w; w += NI64;
  float* Eu_sum = w; w += NU64;
  float* Ei_sum = w; w += NI64;
  float* Zu  = w; w += NU64;
  float* Zdu = w; w += NU64;
  float* Zi  = w; w += NI64;
  float* Zdi = w; w += NI64;
  float* Mu = w; w += 512;
  float* Mi = w; w += 512;
  float* normbuf = w; w += 12 * B64;
  float* hyper = w; w += 16 * B64;
  float* slots = w; w += 16;
  if ((size_t)((char*)w - (char*)d_ws) > ws_size) return;  // ws too small

  // ---- host-side JAX key derivation (partitionable threefry) ----
  auto ksplit = [](uint32_t a, uint32_t b, uint32_t idx, uint32_t& o0, uint32_t& o1) {
    uint32_t x0 = 0u, x1 = idx;
    tf2x32(a, b, x0, x1);
    o0 = x0; o1 = x1;
  };
  uint32_t rk0 = 0u, rk1 = 42u;
  uint32_t lk[2][4][2];  // [layer][k1 dropU, k2 dropI, k3 noiseU, k4 noiseI][pair]
  for (int l = 0; l < 2; ++l) {
    uint32_t n0, n1;
    ksplit(rk0, rk1, 0u, n0, n1);
    for (int i = 0; i < 4; ++i) ksplit(rk0, rk1, (uint32_t)(i + 1), lk[l][i][0], lk[l][i][1]);
    rk0 = n0; rk1 = n1;
  }
  NceKeys nk;
  {
    uint32_t mk0 = 0u, mk1 = 7u;
    for (int i = 0; i < 16; ++i) {
      uint32_t n0, n1;
      ksplit(mk0, mk1, 0u, n0, n1);
      ksplit(mk0, mk1, 1u, nk.k0[i], nk.k1[i]);
      mk0 = n0; mk1 = n1;
    }
  }
  WPtrs wp;
  wp.W[0] = W_ng; wp.W[1] = W_ng + 4096;
  wp.W[2] = W_nn;
  wp.W[3] = W_dg; wp.W[4] = W_dg + 4096;
  wp.W[5] = W_dd;
  wp.W[6] = W_nd; wp.W[7] = W_nd + 4096;

  // ---- init ----
  hipMemcpyAsync(Eu_cur, E_u_0, NU64 * 4, hipMemcpyDeviceToDevice, stream);
  hipMemcpyAsync(Eu_sum, E_u_0, NU64 * 4, hipMemcpyDeviceToDevice, stream);
  hipMemcpyAsync(Ei_cur, E_i_0, NI64 * 4, hipMemcpyDeviceToDevice, stream);
  hipMemcpyAsync(Ei_sum, E_i_0, NI64 * 4, hipMemcpyDeviceToDevice, stream);
  hipMemsetAsync(slots, 0, 16 * 4, stream);

  const int spmm_blocks = (int)(((long long)C_NE * 64 + 255) / 256);
  const int actU_blocks = (int)((NU64 + 255) / 256);
  const int actI_blocks = (int)((NI64 + 255) / 256);
  const int gb = (int)(B64 / 256);  // 1024

  for (int l = 0; l < 2; ++l) {
    // zero accumulators (Zu,Zdu,Zi,Zdi contiguous) and M (Mu,Mi contiguous)
    hipMemsetAsync(Zu, 0, (2 * NU64 + 2 * NI64) * 4, stream);
    hipMemsetAsync(Mu, 0, 1024 * 4, stream);
    // Z_du/Z_u: gather items (cols), scatter to users (rows), dropout key k1
    spmm_kernel<<<spmm_blocks, 256, 0, stream>>>(adjvals, adj_cols, adj_rows,
                                                 Ei_cur, Zu, Zdu,
                                                 lk[l][0][0], lk[l][0][1]);
    // Z_di/Z_i: gather users (rows), scatter to items (cols), dropout key k2
    spmm_kernel<<<spmm_blocks, 256, 0, stream>>>(adjvals, adj_rows, adj_cols,
                                                 Eu_cur, Zi, Zdi,
                                                 lk[l][1][0], lk[l][1][1]);
    // SVD middle matrices from PREVIOUS-level embeddings (before E update)
    svd_reduce<<<1024, 256, 0, stream>>>(vt, Ei_cur, Mu, C_NI);
    svd_reduce<<<1024, 256, 0, stream>>>(ut, Eu_cur, Mi, C_NU);
    // act + noise (k3 u-side, k4 i-side) + E update
    act_noise_update<<<actU_blocks, 256, 0, stream>>>(Zu, Zdu, Eu_cur, Eu_sum,
                                                      lk[l][2][0], lk[l][2][1], C_NU);
    act_noise_update<<<actI_blocks, 256, 0, stream>>>(Zi, Zdi, Ei_cur, Ei_sum,
                                                      lk[l][3][0], lk[l][3][1], C_NI);
    // gather + normalize batch rows: Z, Zd, G
    gather_norm<<<dim3(gb, 3), 256, 0, stream>>>(
        uids, Zu, Zdu, u_mul_s, Mu,
        normbuf + (size_t)(0 + l) * B64, normbuf + (size_t)(4 + l) * B64,
        normbuf + (size_t)(8 + l) * B64);
    gather_norm<<<dim3(gb, 3), 256, 0, stream>>>(
        iids, Zi, Zdi, v_mul_s, Mi,
        normbuf + (size_t)(2 + l) * B64, normbuf + (size_t)(6 + l) * B64,
        normbuf + (size_t)(10 + l) * B64);
  }

  hyper_kernel<<<dim3(gb, 16), 256, 0, stream>>>(normbuf, hyper, wp);
  nce_kernel<<<dim3(C_B / 64, 16), 256, 0, stream>>>(normbuf, hyper, slots, nk);
  loss_r_kernel<<<gb, 256, 0, stream>>>(Eu_sum, Ei_sum, uids, pos, neg, slots);
  final_kernel<<<1, 1, 0, stream>>>(slots, out);
}